// Round 1
// baseline (25396.745 us; speedup 1.0000x reference)
//
#include <hip/hip_runtime.h>
#include <hip/hip_bf16.h>
#include <math.h>

#define L_ 6
#define D_ 1024
#define H_ 16
#define HS_ 64
#define RD_ 16
#define I_ 4096
#define V_ 50304
#define B_ 2
#define T_ 1024
#define NTOK_ 2048

// ---------------------------------------------------------------------------
// Embedding gather: x[tkn, :] = embed_w[ids[tkn], :]
__global__ __launch_bounds__(256) void embed_kernel(const int* __restrict__ ids,
                                                    const float* __restrict__ ew,
                                                    float* __restrict__ x) {
    int tkn = blockIdx.x;
    int tid = threadIdx.x;
    int id = ids[tkn];
    ((float4*)(x + (size_t)tkn * D_))[tid] =
        ((const float4*)(ew + (size_t)id * D_))[tid];
}

// ---------------------------------------------------------------------------
// LayerNorm: one block per token, 256 threads, float4 per thread (D=1024)
__global__ __launch_bounds__(256) void ln_kernel(const float* __restrict__ x,
                                                 const float* __restrict__ s,
                                                 const float* __restrict__ b,
                                                 float* __restrict__ out) {
    int tkn = blockIdx.x;
    int tid = threadIdx.x;
    const float4* xp = (const float4*)(x + (size_t)tkn * D_);
    float4 xv = xp[tid];
    __shared__ float red[256];
    float sum = xv.x + xv.y + xv.z + xv.w;
    red[tid] = sum;
    __syncthreads();
    for (int off = 128; off > 0; off >>= 1) {
        if (tid < off) red[tid] += red[tid + off];
        __syncthreads();
    }
    float mean = red[0] * (1.0f / (float)D_);
    __syncthreads();
    float dx0 = xv.x - mean, dx1 = xv.y - mean, dx2 = xv.z - mean, dx3 = xv.w - mean;
    red[tid] = dx0 * dx0 + dx1 * dx1 + dx2 * dx2 + dx3 * dx3;
    __syncthreads();
    for (int off = 128; off > 0; off >>= 1) {
        if (tid < off) red[tid] += red[tid + off];
        __syncthreads();
    }
    float var = red[0] * (1.0f / (float)D_);
    float r = rsqrtf(var + 1e-5f);
    int d = tid * 4;
    float4 ov;
    ov.x = dx0 * r * s[d + 0] + b[d + 0];
    ov.y = dx1 * r * s[d + 1] + b[d + 1];
    ov.z = dx2 * r * s[d + 2] + b[d + 2];
    ov.w = dx3 * r * s[d + 3] + b[d + 3];
    ((float4*)(out + (size_t)tkn * D_))[tid] = ov;
}

// ---------------------------------------------------------------------------
// Generic tiled fp32 GEMM: C[M,N] = act(A[M,K] @ W[K,N] + bias) + add1 + add2
// BM=BN=64, BK=16, 256 threads, 4x4 micro-tile per thread.
// Requires M%64==0, N%64==0, K%16==0 (true for all shapes here).
#define BM 64
#define BN 64
#define BK 16
__global__ __launch_bounds__(256) void gemm_kernel(
    const float* __restrict__ A, const float* __restrict__ W,
    const float* __restrict__ bias, const float* __restrict__ add1,
    const float* __restrict__ add2, float* __restrict__ C,
    int M, int N, int K, int act) {
    __shared__ float As[BK][BM];
    __shared__ float Bs[BK][BN];
    int tid = threadIdx.x;
    int m0 = blockIdx.y * BM, n0 = blockIdx.x * BN;
    int tx = tid & 15, ty = tid >> 4;
    float acc[4][4] = {};
    int lm = tid >> 2;          // 0..63  (A row within tile)
    int lk4 = (tid & 3) * 4;    // 0,4,8,12 (A k within tile, float4)
    int lkb = tid >> 4;         // 0..15  (W k within tile)
    int lnb = (tid & 15) * 4;   // W n within tile, float4
    for (int k0 = 0; k0 < K; k0 += BK) {
        float4 av = *(const float4*)(A + (size_t)(m0 + lm) * K + k0 + lk4);
        As[lk4 + 0][lm] = av.x;
        As[lk4 + 1][lm] = av.y;
        As[lk4 + 2][lm] = av.z;
        As[lk4 + 3][lm] = av.w;
        *(float4*)&Bs[lkb][lnb] =
            *(const float4*)(W + (size_t)(k0 + lkb) * N + n0 + lnb);
        __syncthreads();
#pragma unroll
        for (int kk = 0; kk < BK; ++kk) {
            float a[4], bb[4];
#pragma unroll
            for (int i = 0; i < 4; ++i) a[i] = As[kk][ty * 4 + i];
#pragma unroll
            for (int j = 0; j < 4; ++j) bb[j] = Bs[kk][tx * 4 + j];
#pragma unroll
            for (int i = 0; i < 4; ++i)
#pragma unroll
                for (int j = 0; j < 4; ++j) acc[i][j] += a[i] * bb[j];
        }
        __syncthreads();
    }
#pragma unroll
    for (int i = 0; i < 4; ++i) {
        int m = m0 + ty * 4 + i;
#pragma unroll
        for (int j = 0; j < 4; ++j) {
            int n = n0 + tx * 4 + j;
            float v = acc[i][j];
            if (bias) v += bias[n];
            if (act == 1) v = 0.5f * v * (1.0f + erff(v * 0.70710678118654752f));
            size_t idx = (size_t)m * N + n;
            if (add1) v += add1[idx];
            if (add2) v += add2[idx];
            C[idx] = v;
        }
    }
}

// ---------------------------------------------------------------------------
// QKV split + RoPE scatter. qkv is (NTOK, H*3*HS) with per-head [q|k|v] of 64.
// Outputs q,k,v in (B*H, T, HS) layout; RoPE applied to first RD dims of q,k.
__global__ __launch_bounds__(64) void rope_scatter_kernel(
    const float* __restrict__ qkv, float* __restrict__ q,
    float* __restrict__ k, float* __restrict__ v) {
    int tkn = blockIdx.x;   // 0..NTOK-1
    int h = blockIdx.y;     // 0..H-1
    int d = threadIdx.x;    // 0..63
    int b = tkn >> 10;      // tkn / T_
    int t = tkn & 1023;     // tkn % T_
    __shared__ float qs[HS_], ks[HS_];
    const float* base = qkv + (size_t)tkn * (3 * D_) + h * (3 * HS_);
    float qv = base[d];
    float kv = base[HS_ + d];
    float vv = base[2 * HS_ + d];
    qs[d] = qv;
    ks[d] = kv;
    __syncthreads();
    if (d < RD_) {
        int i = d & 7;
        float inv = powf(10000.0f, -(float)(2 * i) / (float)RD_);
        float ang = (float)t * inv;
        float c = cosf(ang), s = sinf(ang);
        float qr = (d < 8) ? -qs[d + 8] : qs[d - 8];
        float kr = (d < 8) ? -ks[d + 8] : ks[d - 8];
        qv = qv * c + qr * s;
        kv = kv * c + kr * s;
    }
    size_t out_idx = ((size_t)(b * H_ + h) * T_ + t) * HS_ + d;
    q[out_idx] = qv;
    k[out_idx] = kv;
    v[out_idx] = vv;
}

// ---------------------------------------------------------------------------
// Attention: one block per (query row, b*h). Scores row in LDS, softmax,
// then weighted V sum. Writes att2 in (b, t, h*HS+d) layout (ready for dense).
__global__ __launch_bounds__(256) void attn_kernel(const float* __restrict__ q,
                                                   const float* __restrict__ k,
                                                   const float* __restrict__ v,
                                                   float* __restrict__ att2) {
    int tq = blockIdx.x;   // 0..T-1
    int bh = blockIdx.y;   // 0..B*H-1
    int b = bh >> 4, h = bh & 15;
    int tid = threadIdx.x;
    __shared__ float qs[HS_];
    __shared__ float sc[T_];
    __shared__ float red[256];
    const float* qp = q + ((size_t)bh * T_ + tq) * HS_;
    if (tid < HS_) qs[tid] = qp[tid];
    __syncthreads();
    float svals[4];
    float lmax = -1e30f;
#pragma unroll
    for (int jj = 0; jj < 4; ++jj) {
        int j = jj * 256 + tid;
        const float4* kp = (const float4*)(k + ((size_t)bh * T_ + j) * HS_);
        float s = 0.0f;
#pragma unroll
        for (int d4 = 0; d4 < 16; ++d4) {
            float4 kv = kp[d4];
            s += qs[d4 * 4 + 0] * kv.x + qs[d4 * 4 + 1] * kv.y +
                 qs[d4 * 4 + 2] * kv.z + qs[d4 * 4 + 3] * kv.w;
        }
        s = s * 0.125f + (j > tq ? -10000.0f : 0.0f);
        svals[jj] = s;
        lmax = fmaxf(lmax, s);
    }
    red[tid] = lmax;
    __syncthreads();
    for (int off = 128; off > 0; off >>= 1) {
        if (tid < off) red[tid] = fmaxf(red[tid], red[tid + off]);
        __syncthreads();
    }
    float mx = red[0];
    __syncthreads();
    float lsum = 0.0f;
#pragma unroll
    for (int jj = 0; jj < 4; ++jj) {
        int j = jj * 256 + tid;
        float e = expf(svals[jj] - mx);
        sc[j] = e;
        lsum += e;
    }
    red[tid] = lsum;
    __syncthreads();
    for (int off = 128; off > 0; off >>= 1) {
        if (tid < off) red[tid] += red[tid + off];
        __syncthreads();
    }
    float inv = 1.0f / red[0];
    __syncthreads();
    // weighted V accumulation: thread = (part 0..3, d 0..63)
    int d = tid & 63;
    int part = tid >> 6;
    float acc = 0.0f;
    const float* vp = v + (size_t)bh * T_ * HS_;
    for (int j = part * 256; j < part * 256 + 256; ++j)
        acc += sc[j] * vp[(size_t)j * HS_ + d];
    red[tid] = acc;   // tid == part*64 + d
    __syncthreads();
    if (tid < 64) {
        float o = (red[tid] + red[64 + tid] + red[128 + tid] + red[192 + tid]) * inv;
        att2[((size_t)(b * T_ + tq)) * D_ + h * HS_ + tid] = o;
    }
}

// ---------------------------------------------------------------------------
extern "C" void kernel_launch(void* const* d_in, const int* in_sizes, int n_in,
                              void* d_out, int out_size, void* d_ws, size_t ws_size,
                              hipStream_t stream) {
    const int*   ids     = (const int*)d_in[0];
    const float* embed_w = (const float*)d_in[1];
    const float* ln1_s   = (const float*)d_in[2];
    const float* ln1_b   = (const float*)d_in[3];
    const float* ln2_s   = (const float*)d_in[4];
    const float* ln2_b   = (const float*)d_in[5];
    const float* qkv_w   = (const float*)d_in[6];
    const float* qkv_b   = (const float*)d_in[7];
    const float* dense_w = (const float*)d_in[8];
    const float* dense_b = (const float*)d_in[9];
    const float* fc1_w   = (const float*)d_in[10];
    const float* fc1_b   = (const float*)d_in[11];
    const float* fc2_w   = (const float*)d_in[12];
    const float* fc2_b   = (const float*)d_in[13];
    const float* fln_s   = (const float*)d_in[14];
    const float* fln_b   = (const float*)d_in[15];
    const float* head_w  = (const float*)d_in[16];
    float* out = (float*)d_out;

    const size_t TD = (size_t)NTOK_ * D_;   // 2M floats
    float* ws = (float*)d_ws;
    float* x    = ws;             // TD
    float* h    = x + TD;         // TD
    float* qkv  = h + TD;         // 3*TD
    float* qb   = qkv + 3 * TD;   // TD
    float* kb   = qb + TD;        // TD
    float* vb   = kb + TD;        // TD
    float* att2 = vb + TD;        // TD
    float* attp = att2 + TD;      // TD
    float* mlp1 = attp + TD;      // NTOK*I = 4*TD

    // Embedding
    embed_kernel<<<NTOK_, 256, 0, stream>>>(ids, embed_w, x);

    for (int l = 0; l < L_; ++l) {
        const float* l1s = ln1_s + (size_t)l * D_;
        const float* l1b = ln1_b + (size_t)l * D_;
        const float* l2s = ln2_s + (size_t)l * D_;
        const float* l2b = ln2_b + (size_t)l * D_;
        const float* qw  = qkv_w + (size_t)l * D_ * 3 * D_;
        const float* qbi = qkv_b + (size_t)l * 3 * D_;
        const float* dw  = dense_w + (size_t)l * D_ * D_;
        const float* dbi = dense_b + (size_t)l * D_;
        const float* f1w = fc1_w + (size_t)l * D_ * I_;
        const float* f1b = fc1_b + (size_t)l * I_;
        const float* f2w = fc2_w + (size_t)l * I_ * D_;
        const float* f2b = fc2_b + (size_t)l * D_;

        // h = ln1(x)
        ln_kernel<<<NTOK_, 256, 0, stream>>>(x, l1s, l1b, h);
        // qkv = h @ qw + qb
        gemm_kernel<<<dim3(3 * D_ / BN, NTOK_ / BM), 256, 0, stream>>>(
            h, qw, qbi, nullptr, nullptr, qkv, NTOK_, 3 * D_, D_, 0);
        // split + rope
        rope_scatter_kernel<<<dim3(NTOK_, H_), 64, 0, stream>>>(qkv, qb, kb, vb);
        // attention
        attn_kernel<<<dim3(T_, B_ * H_), 256, 0, stream>>>(qb, kb, vb, att2);
        // attp = att2 @ dw + dbi
        gemm_kernel<<<dim3(D_ / BN, NTOK_ / BM), 256, 0, stream>>>(
            att2, dw, dbi, nullptr, nullptr, attp, NTOK_, D_, D_, 0);
        // h = ln2(x)
        ln_kernel<<<NTOK_, 256, 0, stream>>>(x, l2s, l2b, h);
        // mlp1 = gelu(h @ f1w + f1b)
        gemm_kernel<<<dim3(I_ / BN, NTOK_ / BM), 256, 0, stream>>>(
            h, f1w, f1b, nullptr, nullptr, mlp1, NTOK_, I_, D_, 1);
        // x = mlp1 @ f2w + f2b + attp + x
        gemm_kernel<<<dim3(D_ / BN, NTOK_ / BM), 256, 0, stream>>>(
            mlp1, f2w, f2b, attp, x, x, NTOK_, D_, I_, 0);
    }

    // final ln + head
    ln_kernel<<<NTOK_, 256, 0, stream>>>(x, fln_s, fln_b, h);
    gemm_kernel<<<dim3(V_ / BN, NTOK_ / BM), 256, 0, stream>>>(
        h, head_w, nullptr, nullptr, nullptr, out, NTOK_, V_, D_, 0);
}